// Round 3
// baseline (96512.213 us; speedup 1.0000x reference)
//
#include <hip/hip_runtime.h>
#include <stdint.h>

// ---------------- PRNG variant switches (flip across rounds if mismatch) ----
// SPLIT_PART=1: jax_threefry_partitionable (default since jax 0.4.36):
//   split(key,n) child i = threefry block of counter (0,i), both words
//   scalar 32-bit random_bits = x0 ^ x1 of block (0,0)
// SPLIT_PART=0: original threefry (pair-split over iota(2n); scalar bits = x0)
#define SPLIT_PART 1

namespace {

constexpr int BATCH = 8;
constexpr int NPTS  = 16384;
constexpr int NQ    = 4096;
constexpr int KNN   = 16;
constexpr int BLOCK = 512;            // 8 waves
constexpr int CH    = NPTS / BLOCK;   // 32 points per thread (contiguous chunk)
constexpr int NWAVE = BLOCK / 64;     // 8
constexpr size_t IDX_ELEMS = (size_t)BATCH * NQ * KNN;  // 524288 f32 elems, then pts

// Threefry-2x32, 20 rounds, jax's exact schedule.
__device__ __forceinline__ void tf2x32(uint32_t k0, uint32_t k1,
                                       uint32_t x0, uint32_t x1,
                                       uint32_t &o0, uint32_t &o1) {
  uint32_t ks2 = k0 ^ k1 ^ 0x1BD11BDAu;
  x0 += k0; x1 += k1;
#define TFR(r) { x0 += x1; x1 = (x1 << (r)) | (x1 >> (32 - (r))); x1 ^= x0; }
  TFR(13) TFR(15) TFR(26) TFR(6)
  x0 += k1;  x1 += ks2 + 1u;
  TFR(17) TFR(29) TFR(16) TFR(24)
  x0 += ks2; x1 += k0 + 2u;
  TFR(13) TFR(15) TFR(26) TFR(6)
  x0 += k0;  x1 += k1 + 3u;
  TFR(17) TFR(29) TFR(16) TFR(24)
  x0 += k1;  x1 += ks2 + 4u;
  TFR(13) TFR(15) TFR(26) TFR(6)
  x0 += ks2; x1 += k0 + 5u;
#undef TFR
  o0 = x0; o1 = x1;
}

// child i of jax.random.split(parent, n)
__device__ __forceinline__ void split_child(uint32_t pk0, uint32_t pk1, uint32_t n,
                                            uint32_t i, uint32_t &c0, uint32_t &c1) {
#if SPLIT_PART
  (void)n;
  tf2x32(pk0, pk1, 0u, i, c0, c1);
#else
  uint32_t j0 = 2u * i, j1 = 2u * i + 1u, a0, a1;
  if (j0 < n) { tf2x32(pk0, pk1, j0, j0 + n, a0, a1); c0 = a0; }
  else        { tf2x32(pk0, pk1, j0 - n, j0, a0, a1); c0 = a1; }
  if (j1 < n) { tf2x32(pk0, pk1, j1, j1 + n, a0, a1); c1 = a0; }
  else        { tf2x32(pk0, pk1, j1 - n, j1, a0, a1); c1 = a1; }
#endif
}

// scalar 32-bit draw: _random_bits(key, 32, ())
__device__ __forceinline__ uint32_t bits32_scalar(uint32_t k0, uint32_t k1) {
  uint32_t a0, a1;
  tf2x32(k0, k1, 0u, 0u, a0, a1);
#if SPLIT_PART
  return a0 ^ a1;   // partitionable 32-bit path: bits1 ^ bits2
#else
  return a0;        // original path: x0 word
#endif
}

__device__ __forceinline__ unsigned long long shflxor_u64(unsigned long long v, int m) {
  int lo = __shfl_xor((int)(uint32_t)v, m, 64);
  int hi = __shfl_xor((int)(uint32_t)(v >> 32), m, 64);
  return (((unsigned long long)(uint32_t)hi) << 32) | (uint32_t)lo;
}

} // namespace

__global__ __launch_bounds__(BLOCK, 2)
void snn_sample_kernel(const float* __restrict__ xyz, float* __restrict__ out) {
  const int b    = blockIdx.x;
  const int t    = threadIdx.x;
  const int wave = t >> 6;
  const int lane = t & 63;

  __shared__ __align__(16) uint16_t used[NPTS];            // 32 KB coverage counters
  __shared__ unsigned long long cand[NWAVE * KNN];         // per-wave sorted top-16
  __shared__ uint32_t rngHi[BLOCK];
  __shared__ uint32_t rngLo[BLOCK];
  __shared__ uint32_t wvMin[NWAVE];
  __shared__ uint32_t wvCnt[NWAVE];
  __shared__ uint32_t wvBase[NWAVE];
  __shared__ uint32_t sWin[KNN];
  __shared__ float    sPt[3];
  __shared__ uint32_t sCur, sCnt, sCenter;

  // Register-resident point chunk (contiguous indices => index-ordered scans work)
  float px[CH], py[CH], pz[CH];
  {
    const float* sp = xyz + ((size_t)b * NPTS + (size_t)t * CH) * 3;
    #pragma unroll
    for (int j = 0; j < CH; ++j) {
      px[j] = sp[3 * j + 0];
      py[j] = sp[3 * j + 1];
      pz[j] = sp[3 * j + 2];
    }
  }
  {
    uint32_t* u32p = (uint32_t*)used;
    #pragma unroll
    for (int j = 0; j < CH / 2; ++j) u32p[t * (CH / 2) + j] = 0u;
  }

  // key(42) = (0,42); batch key = split(key42, 8)[b]
  uint32_t kb0, kb1;
  split_child(0u, 42u, (uint32_t)BATCH, (uint32_t)b, kb0, kb1);
  __syncthreads();

  for (int s = 0; s < NQ; ++s) {
    // ---- refill per-step randint words for the next BLOCK steps (parallel) --
    if ((s & (BLOCK - 1)) == 0) {
      uint32_t ss = (uint32_t)(s + t);
      uint32_t ks0, ks1, u0, u1, v0, v1;
      split_child(kb0, kb1, (uint32_t)NQ, ss, ks0, ks1);  // step key
      split_child(ks0, ks1, 2u, 0u, u0, u1);              // k1 (higher bits)
      split_child(ks0, ks1, 2u, 1u, v0, v1);              // k2 (lower bits)
      rngHi[t] = bits32_scalar(u0, u1);
      rngLo[t] = bits32_scalar(v0, v1);
      __syncthreads();
    }

    // ---- phase A: cur = min(used) ------------------------------------------
    uint32_t uw[CH / 2];
    uint32_t mn = 0xFFFFFFFFu;
    {
      const uint32_t* up = (const uint32_t*)used + t * (CH / 2);
      #pragma unroll
      for (int j = 0; j < CH / 2; ++j) {
        uint32_t w = up[j]; uw[j] = w;
        uint32_t a = w & 0xFFFFu, c = w >> 16;
        uint32_t m2 = a < c ? a : c;
        mn = m2 < mn ? m2 : mn;
      }
    }
    #pragma unroll
    for (int m = 1; m < 64; m <<= 1) {
      uint32_t o = (uint32_t)__shfl_xor((int)mn, m, 64);
      mn = o < mn ? o : mn;
    }
    if (lane == 0) wvMin[wave] = mn;
    __syncthreads();
    if (t == 0) {
      uint32_t c = wvMin[0];
      #pragma unroll
      for (int w2 = 1; w2 < NWAVE; ++w2) c = wvMin[w2] < c ? wvMin[w2] : c;
      sCur = c;
    }
    __syncthreads();
    const uint32_t cur = sCur;

    // ---- phase B: cnt, block scan, randint, pick r-th least-used point -----
    uint32_t cl = 0;
    #pragma unroll
    for (int j = 0; j < CH / 2; ++j) {
      uint32_t w = uw[j];
      cl += ((w & 0xFFFFu) == cur) ? 1u : 0u;
      cl += ((w >> 16) == cur) ? 1u : 0u;
    }
    uint32_t incl = cl;
    #pragma unroll
    for (int m = 1; m < 64; m <<= 1) {
      uint32_t v = (uint32_t)__shfl_up((int)incl, (unsigned)m, 64);
      if (lane >= m) incl += v;
    }
    if (lane == 63) wvCnt[wave] = incl;
    __syncthreads();
    if (t == 0) {
      uint32_t acc = 0;
      #pragma unroll
      for (int w2 = 0; w2 < NWAVE; ++w2) { wvBase[w2] = acc; acc += wvCnt[w2]; }
      sCnt = acc;
    }
    __syncthreads();
    {
      const uint32_t span = sCnt;                     // >= 1 always
      const uint32_t hi = rngHi[s & (BLOCK - 1)];
      const uint32_t lo = rngLo[s & (BLOCK - 1)];
      uint32_t mult = 65536u % span;                  // 2^16 % span
      mult = (mult * mult) % span;                    // 2^32 % span
      const uint32_t r = ((hi % span) * mult + (lo % span)) % span;  // jax _randint
      const uint32_t myExcl = wvBase[wave] + (incl - cl);
      if (r >= myExcl && r < myExcl + cl) {           // exactly one owner thread
        const uint32_t need = r - myExcl;
        uint32_t seen = 0; int found = -1;
        float fx = 0.f, fy = 0.f, fz = 0.f;
        #pragma unroll
        for (int j = 0; j < CH; ++j) {                // index-ordered scan
          uint32_t uval = (uw[j >> 1] >> ((j & 1) * 16)) & 0xFFFFu;
          bool mm = (uval == cur);
          bool take = mm && (seen == need) && (found < 0);
          if (take) { found = t * CH + j; fx = px[j]; fy = py[j]; fz = pz[j]; }
          seen += mm ? 1u : 0u;
        }
        sCenter = (uint32_t)found;
        sPt[0] = fx; sPt[1] = fy; sPt[2] = fz;
        float* po = out + IDX_ELEMS + ((size_t)b * NQ + s) * 3;
        po[0] = fx; po[1] = fy; po[2] = fz;          // exact copy of input point
      }
    }
    __syncthreads();
    const float cx = sPt[0], cy = sPt[1], cz = sPt[2];

    // ---- phase C: squared distances, strict RN mul/add (no FMA contraction)
    float d[CH];
    #pragma unroll
    for (int j = 0; j < CH; ++j) {
      float dx = __fsub_rn(px[j], cx);
      float dy = __fsub_rn(py[j], cy);
      float dz = __fsub_rn(pz[j], cz);
      d[j] = __fadd_rn(__fadd_rn(__fmul_rn(dx, dx), __fmul_rn(dy, dy)),
                       __fmul_rn(dz, dz));
    }

    // ---- phase D: per-wave top-16 (sorted), barrier-free shuffle extraction
    // order key = (float_bits(d) << 32) | idx : d >= +0 so bit order == value
    // order, and low idx wins ties => exactly lax.top_k's stable order.
    uint32_t avail = 0xFFFFFFFFu;                     // CH == 32 points
    for (int round = 0; round < KNN; ++round) {
      float bd = __int_as_float(0x7F800000);          // +inf
      int bj = -1;
      #pragma unroll
      for (int j = 0; j < CH; ++j) {
        bool ok = (((avail >> j) & 1u) != 0u) && (d[j] < bd);  // strict < keeps lowest j on tie
        if (ok) { bd = d[j]; bj = j; }
      }
      unsigned long long mykey =
          (((unsigned long long)__float_as_uint(bd)) << 32)
          | (uint32_t)(t * CH + (bj & (CH - 1)));
      unsigned long long wbest = mykey;
      #pragma unroll
      for (int m = 1; m < 64; m <<= 1) {
        unsigned long long o = shflxor_u64(wbest, m);
        if (o < wbest) wbest = o;
      }
      if (mykey == wbest) avail &= ~(1u << (bj & (CH - 1)));
      if (lane == 0) cand[wave * KNN + round] = wbest;
    }
    __syncthreads();

    // ---- phase E: wave 0 merges 8x16 candidates -> global sorted top-16 ----
    if (wave == 0) {
      unsigned long long c2[2];
      #pragma unroll
      for (int m = 0; m < 2; ++m) c2[m] = cand[lane + 64 * m];
      unsigned am = 0x3u;
      for (int round = 0; round < KNN; ++round) {
        unsigned long long best = ~0ull; int bm = 0;
        #pragma unroll
        for (int m = 0; m < 2; ++m) {
          bool ok = (((am >> m) & 1u) != 0u) && (c2[m] < best);
          if (ok) { best = c2[m]; bm = m; }
        }
        unsigned long long wbest = best;
        #pragma unroll
        for (int mm = 1; mm < 64; mm <<= 1) {
          unsigned long long o = shflxor_u64(wbest, mm);
          if (o < wbest) wbest = o;
        }
        if (best == wbest && best != ~0ull) am &= ~(1u << (bm & 1));
        if (lane == 0) {
          uint32_t id = (uint32_t)wbest;
          sWin[round] = id;
          out[((size_t)b * NQ + s) * KNN + round] = (float)id;  // idx as f32 (exact)
        }
      }
    }
    __syncthreads();

    // ---- phase F: used[ids] += 1 then used[center] += 100 (two epochs, like
    //      at[ids].add(1) followed by at[index].add(100)) ---------------------
    if (t < KNN) {
      uint32_t w = sWin[t];
      used[w] = (uint16_t)(used[w] + 1u);   // distinct addresses, race-free
    }
    __syncthreads();
    if (t == 0) {
      uint32_t cidx = sCenter;
      used[cidx] = (uint16_t)(used[cidx] + 100u);
    }
    __syncthreads();
  }
}

extern "C" void kernel_launch(void* const* d_in, const int* in_sizes, int n_in,
                              void* d_out, int out_size, void* d_ws, size_t ws_size,
                              hipStream_t stream) {
  (void)in_sizes; (void)n_in; (void)d_ws; (void)ws_size; (void)out_size;
  const float* xyz = (const float*)d_in[0];
  float* out = (float*)d_out;
  snn_sample_kernel<<<dim3(BATCH), dim3(BLOCK), 0, stream>>>(xyz, out);
}

// Round 4
// 45608.072 us; speedup vs baseline: 2.1161x; 2.1161x over previous
//
#include <hip/hip_runtime.h>
#include <stdint.h>

// Exact replication of jax partitionable-threefry coverage sampling (verified
// R3, absmax=0). This round: restructured step pipeline —
//  * distance top-16 via bitonic selection networks (f32) + exact (d,idx)
//    reconstruction, replacing 16 serial extraction rounds
//  * incremental min(used) via LDS value-histogram (no per-step min sweep)
//  * swizzled `used` layout (conflict-free LDS sweep)

namespace {

constexpr int BATCH = 8;
constexpr int NPTS  = 16384;
constexpr int NQ    = 4096;
constexpr int KNN   = 16;
constexpr int BLOCK = 512;            // 8 waves
constexpr int CH    = NPTS / BLOCK;   // 32 points per thread
constexpr int NWAVE = BLOCK / 64;     // 8
constexpr size_t IDX_ELEMS = (size_t)BATCH * NQ * KNN;  // 524288 f32, then pts
constexpr int HBINS = 1024;

// swizzle: insert 1 u32 word of pad per 32 words (2 u16 per 64 u16)
__device__ __forceinline__ int swz32(int v) { return v + (v >> 5); }
__device__ __forceinline__ int swz16(int w) { return w + 2 * (w >> 6); }

// Threefry-2x32, 20 rounds, jax's exact schedule.
__device__ __forceinline__ void tf2x32(uint32_t k0, uint32_t k1,
                                       uint32_t x0, uint32_t x1,
                                       uint32_t &o0, uint32_t &o1) {
  uint32_t ks2 = k0 ^ k1 ^ 0x1BD11BDAu;
  x0 += k0; x1 += k1;
#define TFR(r) { x0 += x1; x1 = (x1 << (r)) | (x1 >> (32 - (r))); x1 ^= x0; }
  TFR(13) TFR(15) TFR(26) TFR(6)
  x0 += k1;  x1 += ks2 + 1u;
  TFR(17) TFR(29) TFR(16) TFR(24)
  x0 += ks2; x1 += k0 + 2u;
  TFR(13) TFR(15) TFR(26) TFR(6)
  x0 += k0;  x1 += k1 + 3u;
  TFR(17) TFR(29) TFR(16) TFR(24)
  x0 += k1;  x1 += ks2 + 4u;
  TFR(13) TFR(15) TFR(26) TFR(6)
  x0 += ks2; x1 += k0 + 5u;
#undef TFR
  o0 = x0; o1 = x1;
}

__device__ __forceinline__ void split_child(uint32_t pk0, uint32_t pk1,
                                            uint32_t i, uint32_t &c0, uint32_t &c1) {
  tf2x32(pk0, pk1, 0u, i, c0, c1);          // partitionable split
}

__device__ __forceinline__ uint32_t bits32_scalar(uint32_t k0, uint32_t k1) {
  uint32_t a0, a1;
  tf2x32(k0, k1, 0u, 0u, a0, a1);
  return a0 ^ a1;                            // partitionable 32-bit draw
}

__device__ __forceinline__ uint32_t jax_randint(uint32_t hi, uint32_t lo, uint32_t span) {
  uint32_t mult = 65536u % span;
  mult = (mult * mult) % span;               // 2^32 % span
  return ((hi % span) * mult + (lo % span)) % span;
}

__device__ __forceinline__ unsigned long long shflxor_u64(unsigned long long v, int m) {
  int lo = __shfl_xor((int)(uint32_t)v, m, 64);
  int hi = __shfl_xor((int)(uint32_t)(v >> 32), m, 64);
  return (((unsigned long long)(uint32_t)hi) << 32) | (uint32_t)lo;
}

__device__ __forceinline__ void ce_asc(float &a, float &b) {
  float lo = fminf(a, b), hi = fmaxf(a, b); a = lo; b = hi;
}

// full bitonic sort of 16 floats, ascending (standard network, 80 CE)
__device__ __forceinline__ void sort16(float e[16]) {
  #pragma unroll
  for (int k = 2; k <= 16; k <<= 1) {
    #pragma unroll
    for (int j = k >> 1; j > 0; j >>= 1) {
      #pragma unroll
      for (int i = 0; i < 16; ++i) {
        int l = i ^ j;
        if (l > i) {
          if ((i & k) == 0) ce_asc(e[i], e[l]); else ce_asc(e[l], e[i]);
        }
      }
    }
  }
}

// bitonic clean of a 16-element bitonic sequence -> ascending (32 CE)
__device__ __forceinline__ void clean16(float e[16]) {
  #pragma unroll
  for (int j = 8; j > 0; j >>= 1) {
    #pragma unroll
    for (int i = 0; i < 16; ++i) {
      int l = i ^ j;
      if (l > i) ce_asc(e[i], e[l]);
    }
  }
}

} // namespace

__global__ __launch_bounds__(BLOCK, 2)
void snn_sample_kernel(const float* __restrict__ xyz, float* __restrict__ out) {
  const int b    = blockIdx.x;
  const int t    = threadIdx.x;
  const int wave = t >> 6;
  const int lane = t & 63;
  const float INF = __int_as_float(0x7f800000);

  __shared__ __align__(16) uint16_t used[16896];        // swizzled, 33792 B
  __shared__ uint32_t hist[HBINS];                      // counter-value histogram
  __shared__ float    wls[NWAVE * 16];                  // per-wave sorted top-16 d
  __shared__ unsigned long long cnd[64];                // collected (d,idx) keys
  __shared__ uint32_t rngHi[BLOCK];
  __shared__ uint32_t rngLo[BLOCK];
  __shared__ uint32_t wvCnt[NWAVE];
  __shared__ float    sPt[3];
  __shared__ float    sThr;
  __shared__ uint32_t sCur, sSpan, sR, sNc;

  // ---- init --------------------------------------------------------------
  float px[CH], py[CH], pz[CH];
  {
    const float* sp = xyz + ((size_t)b * NPTS + (size_t)t * CH) * 3;
    #pragma unroll
    for (int j = 0; j < CH; ++j) {
      px[j] = sp[3 * j + 0];
      py[j] = sp[3 * j + 1];
      pz[j] = sp[3 * j + 2];
    }
  }
  {
    uint32_t* u32p = (uint32_t*)used;
    for (int i = t; i < 16896 / 2; i += BLOCK) u32p[i] = 0u;
    for (int i = t; i < HBINS; i += BLOCK) hist[i] = 0u;
  }
  __syncthreads();
  if (t == 0) { hist[0] = (uint32_t)NPTS; sCur = 0u; sSpan = (uint32_t)NPTS; }

  uint32_t kb0, kb1;
  split_child(0u, 42u, (uint32_t)b, kb0, kb1);   // batch key of split(key42,8)
  __syncthreads();

  for (int s = 0; s < NQ; ++s) {
    // ---- rng refill for steps [s, s+512) + r for this step -----------------
    if ((s & (BLOCK - 1)) == 0) {
      uint32_t ss = (uint32_t)(s + t);
      uint32_t ks0, ks1, u0, u1, v0, v1;
      split_child(kb0, kb1, ss, ks0, ks1);
      split_child(ks0, ks1, 0u, u0, u1);
      split_child(ks0, ks1, 1u, v0, v1);
      rngHi[t] = bits32_scalar(u0, u1);
      rngLo[t] = bits32_scalar(v0, v1);
      __syncthreads();
      if (t == 0) sR = jax_randint(rngHi[0], rngLo[0], sSpan);
      __syncthreads();
    }
    const uint32_t cur = sCur;
    const uint32_t r   = sR;

    // ---- sweep: count matches (used == cur) in my chunk --------------------
    const uint32_t* up32 = (const uint32_t*)used;
    uint32_t cl = 0;
    #pragma unroll
    for (int j = 0; j < CH / 2; ++j) {
      uint32_t w = up32[swz32(t * (CH / 2) + j)];
      cl += ((w & 0xFFFFu) == cur) ? 1u : 0u;
      cl += ((w >> 16) == cur) ? 1u : 0u;
    }
    uint32_t incl = cl;
    #pragma unroll
    for (int m = 1; m < 64; m <<= 1) {
      uint32_t v = (uint32_t)__shfl_up((int)incl, (unsigned)m, 64);
      if (lane >= m) incl += v;
    }
    if (lane == 63) wvCnt[wave] = incl;
    __syncthreads();                                   // B1
    {
      uint32_t myExcl = incl - cl;
      #pragma unroll
      for (int w2 = 0; w2 < NWAVE; ++w2) myExcl += (w2 < wave) ? wvCnt[w2] : 0u;
      if (r >= myExcl && r < myExcl + cl) {            // unique owner thread
        const uint32_t need = r - myExcl;
        uint32_t seen = 0; int found = -1;
        float fx = 0.f, fy = 0.f, fz = 0.f;
        #pragma unroll
        for (int j = 0; j < CH / 2; ++j) {             // index-ordered re-read
          uint32_t w = up32[swz32(t * (CH / 2) + j)];
          #pragma unroll
          for (int h = 0; h < 2; ++h) {
            uint32_t uval = (h == 0) ? (w & 0xFFFFu) : (w >> 16);
            bool mm = (uval == cur);
            bool take = mm && (seen == need) && (found < 0);
            int jj = 2 * j + h;
            if (take) { found = t * CH + jj; fx = px[jj]; fy = py[jj]; fz = pz[jj]; }
            seen += mm ? 1u : 0u;
          }
        }
        (void)found;
        sPt[0] = fx; sPt[1] = fy; sPt[2] = fz;
        float* po = out + IDX_ELEMS + ((size_t)b * NQ + s) * 3;
        po[0] = fx; po[1] = fy; po[2] = fz;
      }
    }
    if (t == 64) sNc = 0u;                             // reset for collect
    __syncthreads();                                   // B2
    const float cx = sPt[0], cy = sPt[1], cz = sPt[2];

    // ---- distances (strict RN, no FMA contraction — matches np f32) --------
    float dd[CH];
    #pragma unroll
    for (int j = 0; j < CH; ++j) {
      float dx = __fsub_rn(px[j], cx);
      float dy = __fsub_rn(py[j], cy);
      float dz = __fsub_rn(pz[j], cz);
      dd[j] = __fadd_rn(__fadd_rn(__fmul_rn(dx, dx), __fmul_rn(dy, dy)),
                        __fmul_rn(dz, dz));
    }

    // ---- per-lane sorted top-16 of 32 (two sort16 + merge-lower) -----------
    float A[16], B[16];
    #pragma unroll
    for (int i = 0; i < 16; ++i) { A[i] = dd[i]; B[i] = dd[16 + i]; }
    sort16(A); sort16(B);
    float L[16];
    #pragma unroll
    for (int i = 0; i < 16; ++i) L[i] = fminf(A[i], B[15 - i]);
    clean16(L);

    // ---- wave butterfly: all lanes -> wave's sorted top-16 d ---------------
    #pragma unroll
    for (int m = 1; m < 64; m <<= 1) {
      float o[16];
      #pragma unroll
      for (int i = 0; i < 16; ++i) o[i] = __shfl_xor(L[i], m, 64);
      float T[16];
      #pragma unroll
      for (int i = 0; i < 16; ++i) T[i] = fminf(L[i], o[15 - i]);
      clean16(T);
      #pragma unroll
      for (int i = 0; i < 16; ++i) L[i] = T[i];
    }
    if (lane == 0) {
      #pragma unroll
      for (int i = 0; i < 16; ++i) wls[wave * 16 + i] = L[i];
    }
    __syncthreads();                                   // B3

    // ---- wave 0: merge 8 wave-lists -> global 16th-smallest distance ------
    if (wave == 0) {
      float M[16];
      if (lane < NWAVE) {
        #pragma unroll
        for (int i = 0; i < 16; ++i) M[i] = wls[lane * 16 + i];
      } else {
        #pragma unroll
        for (int i = 0; i < 16; ++i) M[i] = INF;
      }
      #pragma unroll
      for (int m = 1; m < NWAVE; m <<= 1) {
        float o[16];
        #pragma unroll
        for (int i = 0; i < 16; ++i) o[i] = __shfl_xor(M[i], m, 64);
        float T[16];
        #pragma unroll
        for (int i = 0; i < 16; ++i) T[i] = fminf(M[i], o[15 - i]);
        clean16(T);
        #pragma unroll
        for (int i = 0; i < 16; ++i) M[i] = T[i];
      }
      if (lane == 0) sThr = M[15];
    }
    __syncthreads();                                   // B4
    const float thr = sThr;

    // ---- collect all (d,idx) with d <= thr (exact winner superset) ---------
    #pragma unroll
    for (int j = 0; j < CH; ++j) {
      if (dd[j] <= thr) {
        uint32_t pos = atomicAdd(&sNc, 1u);
        if (pos < 64u) {
          cnd[pos] = (((unsigned long long)__float_as_uint(dd[j])) << 32)
                     | (uint32_t)(t * CH + j);
        }
      }
    }
    __syncthreads();                                   // B5

    // ---- wave 0: sort candidates, emit top-16, update used/hist/cur/r ------
    if (wave == 0) {
      uint32_t nc = sNc; if (nc > 64u) nc = 64u;
      unsigned long long v = (lane < (int)nc) ? cnd[lane] : ~0ull;
      for (int k = 2; k <= 64; k <<= 1) {
        for (int j = k >> 1; j > 0; j >>= 1) {
          unsigned long long o = shflxor_u64(v, j);
          bool up = ((lane & k) == 0);
          bool keepmin = (((lane & j) == 0) == up);
          unsigned long long mn = (v < o) ? v : o;
          unsigned long long mx = (v < o) ? o : v;
          v = keepmin ? mn : mx;
        }
      }
      // lane i holds rank-i (d,idx); ranks 0..15 are the stable top-16
      if (lane < KNN) {
        uint32_t id = (uint32_t)v;
        out[((size_t)b * NQ + s) * KNN + lane] = (float)id;   // exact in f32
        int a16 = swz16((int)id);
        uint32_t old = used[a16];
        used[a16] = (uint16_t)(old + 1u);                      // +1 neighbors
        uint32_t o0 = old < (HBINS - 1) ? old : (HBINS - 1);
        uint32_t o1 = (old + 1u) < (HBINS - 1) ? (old + 1u) : (HBINS - 1);
        atomicSub(&hist[o0], 1u);
        atomicAdd(&hist[o1], 1u);
      }
      if (lane == 0) {                                         // rank 0 == center
        uint32_t cidx = (uint32_t)v;
        int a16 = swz16((int)cidx);
        uint32_t old = used[a16];                              // sees own +1
        used[a16] = (uint16_t)(old + 100u);                    // +100 center
        uint32_t o0 = old < (HBINS - 1) ? old : (HBINS - 1);
        uint32_t o1 = (old + 100u) < (HBINS - 1) ? (old + 100u) : (HBINS - 1);
        atomicSub(&hist[o0], 1u);
        atomicAdd(&hist[o1], 1u);
        // advance cur (min only increases), publish span and next r
        uint32_t c = cur;
        while (hist[c] == 0u) ++c;
        sCur = c;
        uint32_t sp = hist[c];
        sSpan = sp;
        int ns = s + 1;
        if (ns < NQ && (ns & (BLOCK - 1)) != 0)
          sR = jax_randint(rngHi[ns & (BLOCK - 1)], rngLo[ns & (BLOCK - 1)], sp);
      }
    }
    __syncthreads();                                   // B6 (loop top)
  }
}

extern "C" void kernel_launch(void* const* d_in, const int* in_sizes, int n_in,
                              void* d_out, int out_size, void* d_ws, size_t ws_size,
                              hipStream_t stream) {
  (void)in_sizes; (void)n_in; (void)d_ws; (void)ws_size; (void)out_size;
  const float* xyz = (const float*)d_in[0];
  float* out = (float*)d_out;
  snn_sample_kernel<<<dim3(BATCH), dim3(BLOCK), 0, stream>>>(xyz, out);
}

// Round 5
// 28156.406 us; speedup vs baseline: 3.4277x; 1.6198x over previous
//
#include <hip/hip_runtime.h>
#include <stdint.h>

// Exact replication of jax partitionable-threefry coverage sampling (verified
// R3/R4, absmax=0). R5: replace per-lane top-16 sort + 6-level merge butterfly
// with the thread-min rank-16 bound:
//   U = 16th smallest of the 512 per-thread minima  (>= true 16th-NN distance,
//   since the 16 smallest minima are realized by 16 distinct points)
// then collect {d <= U} (~16-25 pts) and exact-sort them (u64 keys) as before.

namespace {

constexpr int BATCH = 8;
constexpr int NPTS  = 16384;
constexpr int NQ    = 4096;
constexpr int KNN   = 16;
constexpr int BLOCK = 512;            // 8 waves
constexpr int CH    = NPTS / BLOCK;   // 32 points per thread
constexpr int NWAVE = BLOCK / 64;     // 8
constexpr size_t IDX_ELEMS = (size_t)BATCH * NQ * KNN;  // 524288 f32, then pts
constexpr int HBINS = 1024;

// swizzle: insert 1 u32 word of pad per 32 words (2 u16 per 64 u16)
__device__ __forceinline__ int swz32(int v) { return v + (v >> 5); }
__device__ __forceinline__ int swz16(int w) { return w + 2 * (w >> 6); }

// Threefry-2x32, 20 rounds, jax's exact schedule.
__device__ __forceinline__ void tf2x32(uint32_t k0, uint32_t k1,
                                       uint32_t x0, uint32_t x1,
                                       uint32_t &o0, uint32_t &o1) {
  uint32_t ks2 = k0 ^ k1 ^ 0x1BD11BDAu;
  x0 += k0; x1 += k1;
#define TFR(r) { x0 += x1; x1 = (x1 << (r)) | (x1 >> (32 - (r))); x1 ^= x0; }
  TFR(13) TFR(15) TFR(26) TFR(6)
  x0 += k1;  x1 += ks2 + 1u;
  TFR(17) TFR(29) TFR(16) TFR(24)
  x0 += ks2; x1 += k0 + 2u;
  TFR(13) TFR(15) TFR(26) TFR(6)
  x0 += k0;  x1 += k1 + 3u;
  TFR(17) TFR(29) TFR(16) TFR(24)
  x0 += k1;  x1 += ks2 + 4u;
  TFR(13) TFR(15) TFR(26) TFR(6)
  x0 += ks2; x1 += k0 + 5u;
#undef TFR
  o0 = x0; o1 = x1;
}

__device__ __forceinline__ void split_child(uint32_t pk0, uint32_t pk1,
                                            uint32_t i, uint32_t &c0, uint32_t &c1) {
  tf2x32(pk0, pk1, 0u, i, c0, c1);          // partitionable split
}

__device__ __forceinline__ uint32_t bits32_scalar(uint32_t k0, uint32_t k1) {
  uint32_t a0, a1;
  tf2x32(k0, k1, 0u, 0u, a0, a1);
  return a0 ^ a1;                            // partitionable 32-bit draw
}

__device__ __forceinline__ uint32_t jax_randint(uint32_t hi, uint32_t lo, uint32_t span) {
  uint32_t mult = 65536u % span;
  mult = (mult * mult) % span;               // 2^32 % span
  return ((hi % span) * mult + (lo % span)) % span;
}

__device__ __forceinline__ unsigned long long shflxor_u64(unsigned long long v, int m) {
  int lo = __shfl_xor((int)(uint32_t)v, m, 64);
  int hi = __shfl_xor((int)(uint32_t)(v >> 32), m, 64);
  return (((unsigned long long)(uint32_t)hi) << 32) | (uint32_t)lo;
}

__device__ __forceinline__ void ce_asc(float &a, float &b) {
  float lo = fminf(a, b), hi = fmaxf(a, b); a = lo; b = hi;
}

// bitonic clean of a 16-element bitonic sequence -> ascending (32 CE)
__device__ __forceinline__ void clean16(float e[16]) {
  #pragma unroll
  for (int j = 8; j > 0; j >>= 1) {
    #pragma unroll
    for (int i = 0; i < 16; ++i) {
      int l = i ^ j;
      if (l > i) ce_asc(e[i], e[l]);
    }
  }
}

} // namespace

__global__ __launch_bounds__(BLOCK, 2)
void snn_sample_kernel(const float* __restrict__ xyz, float* __restrict__ out) {
  const int b    = blockIdx.x;
  const int t    = threadIdx.x;
  const int wave = t >> 6;
  const int lane = t & 63;
  const float INF = __int_as_float(0x7f800000);

  __shared__ __align__(16) uint16_t used[16896];        // swizzled, 33792 B
  __shared__ uint32_t hist[HBINS];                      // counter-value histogram
  __shared__ float    wls[NWAVE * 16];                  // per-wave sorted 16 minima
  __shared__ unsigned long long cnd[64];                // collected (d,idx) keys
  __shared__ uint32_t rngHi[BLOCK];
  __shared__ uint32_t rngLo[BLOCK];
  __shared__ uint32_t wvCnt[NWAVE];
  __shared__ float    sPt[3];
  __shared__ float    sThr;
  __shared__ uint32_t sCur, sSpan, sR, sNc;

  // ---- init --------------------------------------------------------------
  float px[CH], py[CH], pz[CH];
  {
    const float* sp = xyz + ((size_t)b * NPTS + (size_t)t * CH) * 3;
    #pragma unroll
    for (int j = 0; j < CH; ++j) {
      px[j] = sp[3 * j + 0];
      py[j] = sp[3 * j + 1];
      pz[j] = sp[3 * j + 2];
    }
  }
  {
    uint32_t* u32p = (uint32_t*)used;
    for (int i = t; i < 16896 / 2; i += BLOCK) u32p[i] = 0u;
    for (int i = t; i < HBINS; i += BLOCK) hist[i] = 0u;
  }
  __syncthreads();
  if (t == 0) { hist[0] = (uint32_t)NPTS; sCur = 0u; sSpan = (uint32_t)NPTS; }

  uint32_t kb0, kb1;
  split_child(0u, 42u, (uint32_t)b, kb0, kb1);   // batch key of split(key42,8)
  __syncthreads();

  for (int s = 0; s < NQ; ++s) {
    // ---- rng refill for steps [s, s+512) + r for this step -----------------
    if ((s & (BLOCK - 1)) == 0) {
      uint32_t ss = (uint32_t)(s + t);
      uint32_t ks0, ks1, u0, u1, v0, v1;
      split_child(kb0, kb1, ss, ks0, ks1);
      split_child(ks0, ks1, 0u, u0, u1);
      split_child(ks0, ks1, 1u, v0, v1);
      rngHi[t] = bits32_scalar(u0, u1);
      rngLo[t] = bits32_scalar(v0, v1);
      __syncthreads();
      if (t == 0) sR = jax_randint(rngHi[0], rngLo[0], sSpan);
      __syncthreads();
    }
    const uint32_t cur = sCur;
    const uint32_t r   = sR;

    // ---- sweep: count matches (used == cur) in my chunk --------------------
    const uint32_t* up32 = (const uint32_t*)used;
    uint32_t cl = 0;
    #pragma unroll
    for (int j = 0; j < CH / 2; ++j) {
      uint32_t w = up32[swz32(t * (CH / 2) + j)];
      cl += ((w & 0xFFFFu) == cur) ? 1u : 0u;
      cl += ((w >> 16) == cur) ? 1u : 0u;
    }
    uint32_t incl = cl;
    #pragma unroll
    for (int m = 1; m < 64; m <<= 1) {
      uint32_t v = (uint32_t)__shfl_up((int)incl, (unsigned)m, 64);
      if (lane >= m) incl += v;
    }
    if (lane == 63) wvCnt[wave] = incl;
    __syncthreads();                                   // B1
    {
      uint32_t myExcl = incl - cl;
      #pragma unroll
      for (int w2 = 0; w2 < NWAVE; ++w2) myExcl += (w2 < wave) ? wvCnt[w2] : 0u;
      if (r >= myExcl && r < myExcl + cl) {            // unique owner thread
        const uint32_t need = r - myExcl;
        uint32_t seen = 0; int found = -1;
        float fx = 0.f, fy = 0.f, fz = 0.f;
        #pragma unroll
        for (int j = 0; j < CH / 2; ++j) {             // index-ordered re-read
          uint32_t w = up32[swz32(t * (CH / 2) + j)];
          #pragma unroll
          for (int h = 0; h < 2; ++h) {
            uint32_t uval = (h == 0) ? (w & 0xFFFFu) : (w >> 16);
            bool mm = (uval == cur);
            bool take = mm && (seen == need) && (found < 0);
            int jj = 2 * j + h;
            if (take) { found = t * CH + jj; fx = px[jj]; fy = py[jj]; fz = pz[jj]; }
            seen += mm ? 1u : 0u;
          }
        }
        (void)found;
        sPt[0] = fx; sPt[1] = fy; sPt[2] = fz;
        float* po = out + IDX_ELEMS + ((size_t)b * NQ + s) * 3;
        po[0] = fx; po[1] = fy; po[2] = fz;
      }
    }
    if (t == 64) sNc = 0u;                             // reset for collect
    __syncthreads();                                   // B2
    const float cx = sPt[0], cy = sPt[1], cz = sPt[2];

    // ---- distances (strict RN, no FMA contraction — matches np f32) --------
    float dd[CH];
    float mymin = INF;
    #pragma unroll
    for (int j = 0; j < CH; ++j) {
      float dx = __fsub_rn(px[j], cx);
      float dy = __fsub_rn(py[j], cy);
      float dz = __fsub_rn(pz[j], cz);
      dd[j] = __fadd_rn(__fadd_rn(__fmul_rn(dx, dx), __fmul_rn(dy, dy)),
                        __fmul_rn(dz, dz));
      mymin = fminf(mymin, dd[j]);
    }

    // ---- wave bitonic sort-64 of thread minima (1 value/lane, ascending) ---
    {
      float v = mymin;
      #pragma unroll
      for (int k = 2; k <= 64; k <<= 1) {
        #pragma unroll
        for (int j = k >> 1; j > 0; j >>= 1) {
          float o = __shfl_xor(v, j, 64);
          bool up = ((lane & k) == 0);
          bool keepmin = (((lane & j) == 0) == up);
          float mn = fminf(v, o), mx = fmaxf(v, o);
          v = keepmin ? mn : mx;
        }
      }
      if (lane < 16) wls[wave * 16 + lane] = v;        // wave's 16 smallest minima
    }
    __syncthreads();                                   // B3

    // ---- wave 0: merge 8 sorted-16 lists -> U = 16th smallest of 512 minima
    if (wave == 0) {
      float M[16];
      if (lane < NWAVE) {
        #pragma unroll
        for (int i = 0; i < 16; ++i) M[i] = wls[lane * 16 + i];
      } else {
        #pragma unroll
        for (int i = 0; i < 16; ++i) M[i] = INF;
      }
      #pragma unroll
      for (int m = 1; m < NWAVE; m <<= 1) {
        float o[16];
        #pragma unroll
        for (int i = 0; i < 16; ++i) o[i] = __shfl_xor(M[i], m, 64);
        float T[16];
        #pragma unroll
        for (int i = 0; i < 16; ++i) T[i] = fminf(M[i], o[15 - i]);
        clean16(T);
        #pragma unroll
        for (int i = 0; i < 16; ++i) M[i] = T[i];
      }
      if (lane == 0) sThr = M[15];
    }
    __syncthreads();                                   // B4
    const float thr = sThr;   // U >= true 16th-NN distance (exact bound)

    // ---- collect all (d,idx) with d <= U (superset of true top-16) ---------
    #pragma unroll
    for (int j = 0; j < CH; ++j) {
      if (dd[j] <= thr) {
        uint32_t pos = atomicAdd(&sNc, 1u);
        if (pos < 64u) {
          cnd[pos] = (((unsigned long long)__float_as_uint(dd[j])) << 32)
                     | (uint32_t)(t * CH + j);
        }
      }
    }
    __syncthreads();                                   // B5

    // ---- wave 0: sort candidates, emit top-16, update used/hist/cur/r ------
    if (wave == 0) {
      uint32_t nc = sNc; if (nc > 64u) nc = 64u;
      unsigned long long v = (lane < (int)nc) ? cnd[lane] : ~0ull;
      for (int k = 2; k <= 64; k <<= 1) {
        for (int j = k >> 1; j > 0; j >>= 1) {
          unsigned long long o = shflxor_u64(v, j);
          bool up = ((lane & k) == 0);
          bool keepmin = (((lane & j) == 0) == up);
          unsigned long long mn = (v < o) ? v : o;
          unsigned long long mx = (v < o) ? o : v;
          v = keepmin ? mn : mx;
        }
      }
      // lane i holds rank-i (d,idx); ranks 0..15 are the stable top-16
      if (lane < KNN) {
        uint32_t id = (uint32_t)v;
        out[((size_t)b * NQ + s) * KNN + lane] = (float)id;   // exact in f32
        int a16 = swz16((int)id);
        uint32_t old = used[a16];
        used[a16] = (uint16_t)(old + 1u);                      // +1 neighbors
        uint32_t o0 = old < (HBINS - 1) ? old : (HBINS - 1);
        uint32_t o1 = (old + 1u) < (HBINS - 1) ? (old + 1u) : (HBINS - 1);
        atomicSub(&hist[o0], 1u);
        atomicAdd(&hist[o1], 1u);
      }
      if (lane == 0) {                                         // rank 0 == center
        uint32_t cidx = (uint32_t)v;
        int a16 = swz16((int)cidx);
        uint32_t old = used[a16];                              // sees own +1
        used[a16] = (uint16_t)(old + 100u);                    // +100 center
        uint32_t o0 = old < (HBINS - 1) ? old : (HBINS - 1);
        uint32_t o1 = (old + 100u) < (HBINS - 1) ? (old + 100u) : (HBINS - 1);
        atomicSub(&hist[o0], 1u);
        atomicAdd(&hist[o1], 1u);
        // advance cur (min only increases), publish span and next r
        uint32_t c = cur;
        while (hist[c] == 0u) ++c;
        sCur = c;
        uint32_t sp = hist[c];
        sSpan = sp;
        int ns = s + 1;
        if (ns < NQ && (ns & (BLOCK - 1)) != 0)
          sR = jax_randint(rngHi[ns & (BLOCK - 1)], rngLo[ns & (BLOCK - 1)], sp);
      }
    }
    __syncthreads();                                   // B6 (loop top)
  }
}

extern "C" void kernel_launch(void* const* d_in, const int* in_sizes, int n_in,
                              void* d_out, int out_size, void* d_ws, size_t ws_size,
                              hipStream_t stream) {
  (void)in_sizes; (void)n_in; (void)d_ws; (void)ws_size; (void)out_size;
  const float* xyz = (const float*)d_in[0];
  float* out = (float*)d_out;
  snn_sample_kernel<<<dim3(BATCH), dim3(BLOCK), 0, stream>>>(xyz, out);
}

// Round 6
// 23157.320 us; speedup vs baseline: 4.1677x; 1.2159x over previous
//
#include <hip/hip_runtime.h>
#include <stdint.h>

// Exact replication of jax partitionable-threefry coverage sampling (verified
// R3/R4/R5, absmax=0). R6: incremental least-used set (bitmask + per-wave
// sums) replaces the per-step used sweep; redundant per-thread r/span and
// per-wave threshold merge remove two barriers and all serial broadcasts;
// hist removed (span == sum(waveSum), rebuild-on-empty).

namespace {

constexpr int BATCH = 8;
constexpr int NPTS  = 16384;
constexpr int NQ    = 4096;
constexpr int KNN   = 16;
constexpr int BLOCK = 512;            // 8 waves
constexpr int CH    = NPTS / BLOCK;   // 32 points per thread
constexpr int NWAVE = BLOCK / 64;     // 8
constexpr size_t IDX_ELEMS = (size_t)BATCH * NQ * KNN;  // 524288 f32, then pts

// swizzle: insert 1 u32 word of pad per 32 words (2 u16 per 64 u16)
__device__ __forceinline__ int swz32(int v) { return v + (v >> 5); }
__device__ __forceinline__ int swz16(int w) { return w + 2 * (w >> 6); }

// Threefry-2x32, 20 rounds, jax's exact schedule.
__device__ __forceinline__ void tf2x32(uint32_t k0, uint32_t k1,
                                       uint32_t x0, uint32_t x1,
                                       uint32_t &o0, uint32_t &o1) {
  uint32_t ks2 = k0 ^ k1 ^ 0x1BD11BDAu;
  x0 += k0; x1 += k1;
#define TFR(r) { x0 += x1; x1 = (x1 << (r)) | (x1 >> (32 - (r))); x1 ^= x0; }
  TFR(13) TFR(15) TFR(26) TFR(6)
  x0 += k1;  x1 += ks2 + 1u;
  TFR(17) TFR(29) TFR(16) TFR(24)
  x0 += ks2; x1 += k0 + 2u;
  TFR(13) TFR(15) TFR(26) TFR(6)
  x0 += k0;  x1 += k1 + 3u;
  TFR(17) TFR(29) TFR(16) TFR(24)
  x0 += k1;  x1 += ks2 + 4u;
  TFR(13) TFR(15) TFR(26) TFR(6)
  x0 += ks2; x1 += k0 + 5u;
#undef TFR
  o0 = x0; o1 = x1;
}

__device__ __forceinline__ void split_child(uint32_t pk0, uint32_t pk1,
                                            uint32_t i, uint32_t &c0, uint32_t &c1) {
  tf2x32(pk0, pk1, 0u, i, c0, c1);          // partitionable split
}

__device__ __forceinline__ uint32_t bits32_scalar(uint32_t k0, uint32_t k1) {
  uint32_t a0, a1;
  tf2x32(k0, k1, 0u, 0u, a0, a1);
  return a0 ^ a1;                            // partitionable 32-bit draw
}

__device__ __forceinline__ uint32_t jax_randint(uint32_t hi, uint32_t lo, uint32_t span) {
  uint32_t mult = 65536u % span;
  mult = (mult * mult) % span;               // 2^32 % span
  return ((hi % span) * mult + (lo % span)) % span;
}

__device__ __forceinline__ unsigned long long shflxor_u64(unsigned long long v, int m) {
  int lo = __shfl_xor((int)(uint32_t)v, m, 64);
  int hi = __shfl_xor((int)(uint32_t)(v >> 32), m, 64);
  return (((unsigned long long)(uint32_t)hi) << 32) | (uint32_t)lo;
}

__device__ __forceinline__ void ce_asc(float &a, float &b) {
  float lo = fminf(a, b), hi = fmaxf(a, b); a = lo; b = hi;
}

// bitonic clean of a 16-element bitonic sequence -> ascending (32 CE)
__device__ __forceinline__ void clean16(float e[16]) {
  #pragma unroll
  for (int j = 8; j > 0; j >>= 1) {
    #pragma unroll
    for (int i = 0; i < 16; ++i) {
      int l = i ^ j;
      if (l > i) ce_asc(e[i], e[l]);
    }
  }
}

// n-th (0-based) set bit of m, n < popcount(m)
__device__ __forceinline__ uint32_t nth_set_bit(uint32_t m, uint32_t n) {
  uint32_t pos = 0;
  #pragma unroll
  for (int sh = 16; sh > 0; sh >>= 1) {
    uint32_t c = __popc(m & ((1u << sh) - 1u));
    if (n >= c) { n -= c; m >>= sh; pos += sh; }
  }
  return pos;
}

} // namespace

__global__ __launch_bounds__(BLOCK, 2)
void snn_sample_kernel(const float* __restrict__ xyz, float* __restrict__ out) {
  const int b    = blockIdx.x;
  const int t    = threadIdx.x;
  const int wave = t >> 6;
  const int lane = t & 63;
  const float INF = __int_as_float(0x7f800000);

  __shared__ __align__(16) uint16_t used[16896];        // swizzled, 33792 B
  __shared__ uint32_t mask[BLOCK];      // bit j of word t: used[t*32+j]==cur
  __shared__ uint32_t waveSum[NWAVE];   // popcount per wave's 2048-pt chunk
  __shared__ uint32_t wvMin[NWAVE];     // rebuild scratch
  __shared__ float    wls[NWAVE * 16];  // per-wave sorted 16 smallest minima
  __shared__ unsigned long long cnd[64];
  __shared__ uint32_t rngHi[BLOCK];
  __shared__ uint32_t rngLo[BLOCK];
  __shared__ float    sPt[3];
  __shared__ uint32_t sNc, sCur;

  // ---- init --------------------------------------------------------------
  float px[CH], py[CH], pz[CH];
  {
    const float* sp = xyz + ((size_t)b * NPTS + (size_t)t * CH) * 3;
    #pragma unroll
    for (int j = 0; j < CH; ++j) {
      px[j] = sp[3 * j + 0];
      py[j] = sp[3 * j + 1];
      pz[j] = sp[3 * j + 2];
    }
  }
  {
    uint32_t* u32p = (uint32_t*)used;
    for (int i = t; i < 16896 / 2; i += BLOCK) u32p[i] = 0u;
  }
  mask[t] = 0xFFFFFFFFu;
  if (t < NWAVE) waveSum[t] = (uint32_t)(NPTS / NWAVE);   // 2048
  if (t == 0) { sNc = 0u; sCur = 0u; }

  uint32_t kb0, kb1;
  split_child(0u, 42u, (uint32_t)b, kb0, kb1);   // batch key of split(key42,8)
  __syncthreads();

  for (int s = 0; s < NQ; ++s) {
    // ---- rng refill for steps [s, s+512) -----------------------------------
    if ((s & (BLOCK - 1)) == 0) {
      uint32_t ss = (uint32_t)(s + t);
      uint32_t ks0, ks1, u0, u1, v0, v1;
      split_child(kb0, kb1, ss, ks0, ks1);
      split_child(ks0, ks1, 0u, u0, u1);
      split_child(ks0, ks1, 1u, v0, v1);
      rngHi[t] = bits32_scalar(u0, u1);
      rngLo[t] = bits32_scalar(v0, v1);
      __syncthreads();
    }

    // ---- P1: span/r (redundant per thread), owner find ---------------------
    uint32_t ws[NWAVE];
    uint32_t span = 0;
    #pragma unroll
    for (int w = 0; w < NWAVE; ++w) { ws[w] = waveSum[w]; span += ws[w]; }
    uint32_t cur = sCur;

    if (span == 0u) {                    // rare rebuild: cur advanced
      uint32_t uvals[CH / 2];
      uint32_t mn = 0xFFFFFFFFu;
      const uint32_t* up32 = (const uint32_t*)used;
      #pragma unroll
      for (int j = 0; j < CH / 2; ++j) {
        uint32_t w2 = up32[swz32(t * (CH / 2) + j)];
        uvals[j] = w2;
        uint32_t a = w2 & 0xFFFFu, c = w2 >> 16;
        uint32_t m2 = a < c ? a : c;
        mn = m2 < mn ? m2 : mn;
      }
      #pragma unroll
      for (int m = 1; m < 64; m <<= 1) {
        uint32_t o = (uint32_t)__shfl_xor((int)mn, m, 64);
        mn = o < mn ? o : mn;
      }
      if (lane == 0) wvMin[wave] = mn;
      __syncthreads();
      uint32_t c = wvMin[0];
      #pragma unroll
      for (int w = 1; w < NWAVE; ++w) c = wvMin[w] < c ? wvMin[w] : c;
      cur = c;
      if (t == 0) sCur = c;
      uint32_t mw = 0;
      #pragma unroll
      for (int j = 0; j < CH / 2; ++j) {
        uint32_t w2 = uvals[j];
        if ((w2 & 0xFFFFu) == cur) mw |= 1u << (2 * j);
        if ((w2 >> 16)     == cur) mw |= 1u << (2 * j + 1);
      }
      mask[t] = mw;
      uint32_t pc = __popc(mw);
      #pragma unroll
      for (int m = 1; m < 64; m <<= 1) pc += (uint32_t)__shfl_xor((int)pc, m, 64);
      if (lane == 0) waveSum[wave] = pc;
      __syncthreads();
      span = 0;
      #pragma unroll
      for (int w = 0; w < NWAVE; ++w) { ws[w] = waveSum[w]; span += ws[w]; }
    }

    const uint32_t r = jax_randint(rngHi[s & (BLOCK - 1)],
                                   rngLo[s & (BLOCK - 1)], span);
    uint32_t preWave = 0;
    #pragma unroll
    for (int w = 0; w < NWAVE; ++w) preWave += (w < wave) ? ws[w] : 0u;
    if (r >= preWave && r < preWave + ws[wave]) {      // owner wave only
      uint32_t mw = mask[t];
      uint32_t pc = __popc(mw);
      uint32_t incl = pc;
      #pragma unroll
      for (int m = 1; m < 64; m <<= 1) {
        uint32_t v = (uint32_t)__shfl_up((int)incl, (unsigned)m, 64);
        if (lane >= m) incl += v;
      }
      uint32_t myBase = preWave + (incl - pc);
      if (r >= myBase && r < myBase + pc) {            // unique owner thread
        uint32_t pos = nth_set_bit(mw, r - myBase);
        uint32_t id = (uint32_t)t * CH + pos;
        const float* gp = xyz + ((size_t)b * NPTS + id) * 3;
        float fx = gp[0], fy = gp[1], fz = gp[2];
        sPt[0] = fx; sPt[1] = fy; sPt[2] = fz;
        float* po = out + IDX_ELEMS + ((size_t)b * NQ + s) * 3;
        po[0] = fx; po[1] = fy; po[2] = fz;
      }
    }
    __syncthreads();                                   // B2
    const float cx = sPt[0], cy = sPt[1], cz = sPt[2];

    // ---- P2: distances (strict RN, no FMA) + thread-min + wave sort-64 -----
    float dd[CH];
    float mymin = INF;
    #pragma unroll
    for (int j = 0; j < CH; ++j) {
      float dx = __fsub_rn(px[j], cx);
      float dy = __fsub_rn(py[j], cy);
      float dz = __fsub_rn(pz[j], cz);
      dd[j] = __fadd_rn(__fadd_rn(__fmul_rn(dx, dx), __fmul_rn(dy, dy)),
                        __fmul_rn(dz, dz));
      mymin = fminf(mymin, dd[j]);
    }
    {
      float v = mymin;
      #pragma unroll
      for (int k = 2; k <= 64; k <<= 1) {
        #pragma unroll
        for (int j = k >> 1; j > 0; j >>= 1) {
          float o = __shfl_xor(v, j, 64);
          bool up = ((lane & k) == 0);
          bool keepmin = (((lane & j) == 0) == up);
          float mn = fminf(v, o), mx = fmaxf(v, o);
          v = keepmin ? mn : mx;
        }
      }
      if (lane < 16) wls[wave * 16 + lane] = v;
    }
    __syncthreads();                                   // B3

    // ---- P3: every wave redundantly merges 8 lists -> U (no extra barrier) -
    float thr;
    {
      float M[16];
      if (lane < NWAVE) {
        #pragma unroll
        for (int i = 0; i < 16; ++i) M[i] = wls[lane * 16 + i];
      } else {
        #pragma unroll
        for (int i = 0; i < 16; ++i) M[i] = INF;
      }
      #pragma unroll
      for (int m = 1; m < NWAVE; m <<= 1) {
        float o[16];
        #pragma unroll
        for (int i = 0; i < 16; ++i) o[i] = __shfl_xor(M[i], m, 64);
        float T[16];
        #pragma unroll
        for (int i = 0; i < 16; ++i) T[i] = fminf(M[i], o[15 - i]);
        clean16(T);
        #pragma unroll
        for (int i = 0; i < 16; ++i) M[i] = T[i];
      }
      thr = __shfl(M[15], 0, 64);   // U >= true 16th-NN distance (exact bound)
    }

    // ---- P4: collect all (d,idx) with d <= U (superset of true top-16) -----
    #pragma unroll
    for (int j = 0; j < CH; ++j) {
      if (dd[j] <= thr) {
        uint32_t pos = atomicAdd(&sNc, 1u);
        if (pos < 64u) {
          cnd[pos] = (((unsigned long long)__float_as_uint(dd[j])) << 32)
                     | (uint32_t)(t * CH + j);
        }
      }
    }
    __syncthreads();                                   // B5

    // ---- P5: wave 0 sorts candidates, emits top-16, updates state ----------
    if (wave == 0) {
      uint32_t nc = sNc; if (nc > 64u) nc = 64u;
      unsigned long long v = (lane < (int)nc) ? cnd[lane] : ~0ull;
      if (lane == 17) sNc = 0u;       // reset after loads (in-wave order)
      #pragma unroll
      for (int k = 2; k <= 32; k <<= 1) {
        #pragma unroll
        for (int j = k >> 1; j > 0; j >>= 1) {
          unsigned long long o = shflxor_u64(v, j);
          bool up = ((lane & k) == 0);
          bool keepmin = (((lane & j) == 0) == up);
          unsigned long long mn = (v < o) ? v : o;
          unsigned long long mx = (v < o) ? o : v;
          v = keepmin ? mn : mx;
        }
      }
      if (nc > 32u) {                 // finish full sort-64 only if needed
        #pragma unroll
        for (int j = 32; j > 0; j >>= 1) {
          unsigned long long o = shflxor_u64(v, j);
          bool keepmin = ((lane & j) == 0);
          unsigned long long mn = (v < o) ? v : o;
          unsigned long long mx = (v < o) ? o : v;
          v = keepmin ? mn : mx;
        }
      }
      // lane i holds rank-i (d,idx); ranks 0..15 are the stable top-16
      if (lane < KNN) {
        uint32_t id = (uint32_t)v;
        out[((size_t)b * NQ + s) * KNN + lane] = (float)id;   // exact in f32
        int a16 = swz16((int)id);
        uint32_t old = used[a16];
        used[a16] = (uint16_t)(old + 1u);                     // +1 neighbors
        if (old == cur) {                                     // leaves the set
          atomicAnd(&mask[id >> 5], ~(1u << (id & 31u)));
          atomicSub(&waveSum[id >> 11], 1u);
        }
      }
      if (lane == 0) {                                        // rank 0 == center
        uint32_t cidx = (uint32_t)v;
        int a16 = swz16((int)cidx);
        uint32_t old = used[a16];                             // sees own +1
        used[a16] = (uint16_t)(old + 100u);                   // +100 center
      }
    }
    __syncthreads();                                   // B6 (loop top)
  }
}

extern "C" void kernel_launch(void* const* d_in, const int* in_sizes, int n_in,
                              void* d_out, int out_size, void* d_ws, size_t ws_size,
                              hipStream_t stream) {
  (void)in_sizes; (void)n_in; (void)d_ws; (void)ws_size; (void)out_size;
  const float* xyz = (const float*)d_in[0];
  float* out = (float*)d_out;
  snn_sample_kernel<<<dim3(BATCH), dim3(BLOCK), 0, stream>>>(xyz, out);
}